// Round 3
// baseline (361.795 us; speedup 1.0000x reference)
//
#include <hip/hip_runtime.h>

#define NROW 524288
#define KDIM 66
#define NSEG 65
#define NB   2048
#define TILES (NROW / 64)      // 8192
#define PART_STRIDE 12

// ws layout: [0, 528): float weights wI[66], wJ[66]
//            [528, 528 + NB*12*8): double partials (10 h1 accs, sum_soc, sum_soc2)
#define WOFF_P 528

// ---------------------------------------------------------------------------
// Setup: derive the two 66-element evaluation weight vectors at runtime.
// r(t) for row y is linear in y:  r = alpha*s_k + beta*s_{k+1} + gamma*m_k + y_k
// with A s = b, b linear in slopes, slopes linear in y. We solve
// A^T z = alpha*e_k + beta*e_{k+1} (Thomas, f64) and push the linear maps back
// to y-space. Thread 0 handles t=i, thread 1 handles t=j (independent solves).
// ---------------------------------------------------------------------------
__global__ void setup_kernel(const float* __restrict__ ti,
                             const float* __restrict__ tj,
                             float* __restrict__ wout) {
    int tid = threadIdx.x;
    if (tid >= 2) return;
    float t = (tid == 0) ? ti[0] : tj[0];
    float* wo = wout + tid * KDIM;

    // Replicate np.linspace(0,1,66).astype(f32) and np.diff in f32.
    float xk[KDIM];
    float dxf[NSEG];
    double step = 1.0 / 65.0;
    for (int k = 0; k < KDIM; ++k) xk[k] = (float)(step * (double)k);
    xk[KDIM - 1] = 1.0f;
    for (int k = 0; k < NSEG; ++k) dxf[k] = xk[k + 1] - xk[k];

    // searchsorted(xk, t, 'right') - 1, clipped to [0, K-2]
    int kk = 0;
    for (int k = 0; k < KDIM; ++k) if (xk[k] <= t) kk = k;
    if (kk > KDIM - 2) kk = KDIM - 2;

    double h  = (double)(xk[kk + 1] - xk[kk]);
    double u  = (double)(t - xk[kk]);
    double u2 = u * u, u3 = u2 * u, h2 = h * h;
    double alpha = u3 / h2 - 2.0 * u2 / h + u;
    double beta  = u3 / h2 - u2 / h;
    double gamma = 3.0 * u2 / h - 2.0 * u3 / h2;

    double d02 = (double)(xk[2] - xk[0]);
    double dl  = (double)(xk[KDIM - 1] - xk[KDIM - 3]);

    // A^T tridiagonal (av = lower, bv = diag, cv = upper)
    double av[KDIM], bv[KDIM], cv[KDIM];
    bv[0] = (double)dxf[1];
    bv[KDIM - 1] = (double)dxf[KDIM - 3];
    for (int i = 1; i < KDIM - 1; ++i)
        bv[i] = 2.0 * ((double)dxf[i] + (double)dxf[i - 1]);
    av[0] = 0.0;
    av[1] = d02;
    for (int i = 2; i < KDIM; ++i) av[i] = (double)dxf[i - 2];
    for (int i = 0; i < KDIM - 2; ++i) cv[i] = (double)dxf[i + 1];
    cv[KDIM - 2] = dl;
    cv[KDIM - 1] = 0.0;

    double rhs[KDIM];
    for (int i = 0; i < KDIM; ++i) rhs[i] = 0.0;
    rhs[kk]     = alpha;
    rhs[kk + 1] = beta;

    // Thomas solve A^T z = rhs
    double cp[KDIM], dp[KDIM], z[KDIM];
    cp[0] = cv[0] / bv[0];
    dp[0] = rhs[0] / bv[0];
    for (int i = 1; i < KDIM; ++i) {
        double w = bv[i] - av[i] * cp[i - 1];
        cp[i] = cv[i] / w;
        dp[i] = (rhs[i] - av[i] * dp[i - 1]) / w;
    }
    z[KDIM - 1] = dp[KDIM - 1];
    for (int i = KDIM - 2; i >= 0; --i) z[i] = dp[i] - cp[i] * z[i + 1];

    // b-space -> slope-space:
    // b0 = p*slope0 + q*slope1 ; b[k] = 3 dx[k] slope[k-1] + 3 dx[k-1] slope[k]
    // b65 = r1*slope63 + r2*slope64
    double wsl[NSEG];
    for (int m = 0; m < NSEG; ++m) wsl[m] = 0.0;
    double pp = ((double)dxf[0] + 2.0 * d02) * (double)dxf[1] / d02;
    double qq = (double)dxf[0] * (double)dxf[0] / d02;
    wsl[0] += z[0] * pp;
    wsl[1] += z[0] * qq;
    for (int j = 1; j <= NSEG - 1; ++j) {   // j = 1..64
        wsl[j - 1] += z[j] * 3.0 * (double)dxf[j];
        wsl[j]     += z[j] * 3.0 * (double)dxf[j - 1];
    }
    double r1 = (double)dxf[64] * (double)dxf[64] / dl;
    double r2 = (2.0 * dl + (double)dxf[64]) * (double)dxf[63] / dl;
    wsl[63] += z[KDIM - 1] * r1;
    wsl[64] += z[KDIM - 1] * r2;
    wsl[kk] += gamma;                        // the slope_k term in r(t)

    // slope-space -> y-space: slope[m] = (y[m+1]-y[m])/dx[m]
    double wy[KDIM];
    for (int k = 0; k < KDIM; ++k) wy[k] = 0.0;
    for (int m = 0; m < NSEG; ++m) {
        double w = wsl[m] / (double)dxf[m];
        wy[m + 1] += w;
        wy[m]     -= w;
    }
    wy[kk] += 1.0;                           // the y_k term

    for (int k = 0; k < KDIM; ++k) wo[k] = (float)wy[k];
}

// ---------------------------------------------------------------------------
// Main streaming pass: one wave per block; block stages 64 rows (16.9 KB) into
// LDS with coalesced float4 loads (+float2 tail), lane l dots row l against
// wI/wJ, writes ndis, and accumulates W1-partials + soc sums in f64 registers.
// W1/soc for the tile are prefetched BEFORE the staging burst so the vmcnt
// drain for the ds_writes also retires them (no post-dot global stall).
// Per-block partials go to distinct ws slots (no atomics).
// ---------------------------------------------------------------------------
__global__ __launch_bounds__(64) void main_kernel(
    const float* __restrict__ x, const float* __restrict__ soc,
    const float* __restrict__ W1, const float* __restrict__ wglob,
    float* __restrict__ out_ndis, double* __restrict__ partials)
{
    __shared__ float tile[64 * KDIM];       // 16896 B
    __shared__ float wlds[2 * KDIM];        // 528 B
    const int lane = threadIdx.x;

    wlds[lane]      = wglob[lane];
    wlds[64 + lane] = wglob[64 + lane];
    if (lane < 2 * KDIM - 128) wlds[128 + lane] = wglob[128 + lane];

    double accw[10];
#pragma unroll
    for (int o = 0; o < 10; ++o) accw[o] = 0.0;
    double accs = 0.0, accs2 = 0.0;

    for (int t = blockIdx.x; t < TILES; t += NB) {
        const int n = t * 64 + lane;

        // Prefetch the 11 independent per-row operands first; they complete
        // under the staging-drain below.
        float w1v[10];
#pragma unroll
        for (int o = 0; o < 10; ++o) w1v[o] = W1[(size_t)o * NROW + n];
        float socv = soc[n];

        __syncthreads();    // protect LDS reuse (and weight visibility, iter 0)
        // 64 rows x 66 f32 = 16896 B: 16 float4 bursts (16384 B) + 64 float2 tail.
        const float4* __restrict__ src4 =
            (const float4*)(x + (size_t)t * (64 * KDIM));
        float4* dst4 = (float4*)tile;
#pragma unroll
        for (int it = 0; it < 16; ++it)
            dst4[it * 64 + lane] = src4[it * 64 + lane];
        const float2* __restrict__ src2 =
            (const float2*)(x + (size_t)t * (64 * KDIM)) + 2048;
        ((float2*)tile)[2048 + lane] = src2[lane];
        __syncthreads();

        const float2* row = (const float2*)tile + lane * (KDIM / 2);  // stride 264 B: 2-way bank alias (free)
        const float2* wi2 = (const float2*)wlds;
        const float2* wj2 = wi2 + (KDIM / 2);
        float ri = 0.f, rj = 0.f;
#pragma unroll
        for (int k = 0; k < KDIM / 2; ++k) {
            float2 v = row[k];
            float2 a = wi2[k];
            float2 b = wj2[k];
            ri = fmaf(v.x, a.x, ri); ri = fmaf(v.y, a.y, ri);
            rj = fmaf(v.x, b.x, rj); rj = fmaf(v.y, b.y, rj);
        }

        float nd = (ri - rj) / (ri + rj);
        out_ndis[n] = nd;

        double ndd = (double)nd;
#pragma unroll
        for (int o = 0; o < 10; ++o)
            accw[o] = fma((double)w1v[o], ndd, accw[o]);
        double sv = (double)socv;
        accs  += sv;
        accs2  = fma(sv, sv, accs2);
    }

    // wave-level reduction of the 12 f64 accumulators
#pragma unroll
    for (int o = 0; o < 10; ++o) {
        double v = accw[o];
#pragma unroll
        for (int off = 32; off > 0; off >>= 1) v += __shfl_down(v, off, 64);
        accw[o] = v;
    }
    {
        double v = accs;
#pragma unroll
        for (int off = 32; off > 0; off >>= 1) v += __shfl_down(v, off, 64);
        accs = v;
        v = accs2;
#pragma unroll
        for (int off = 32; off > 0; off >>= 1) v += __shfl_down(v, off, 64);
        accs2 = v;
    }
    if (lane == 0) {
        double* p = partials + (size_t)blockIdx.x * PART_STRIDE;
#pragma unroll
        for (int o = 0; o < 10; ++o) p[o] = accw[o];
        p[10] = accs;
        p[11] = accs2;
    }
}

// ---------------------------------------------------------------------------
// Finalize: reduce 2048x12 partials, apply b1 / leaky-relu / W2 / b2, and the
// closed-form loss  N*s^2 - 2*s*sum(soc) + sum(soc^2).
// ---------------------------------------------------------------------------
__global__ void finalize_kernel(const double* __restrict__ partials,
                                const float* __restrict__ b1,
                                const float* __restrict__ W2,
                                const float* __restrict__ b2,
                                float* __restrict__ out)
{
    __shared__ double red[16][16];
    __shared__ double totals[12];
    int tid = threadIdx.x;
    int o = tid & 15, g = tid >> 4;     // 16 groups x 16 slots (12 used)
    double s = 0.0;
    if (o < 12) {
        for (int b = g; b < NB; b += 16)
            s += partials[(size_t)b * PART_STRIDE + o];
    }
    red[g][o] = s;
    __syncthreads();
    if (tid < 12) {
        double tot = 0.0;
        for (int g2 = 0; g2 < 16; ++g2) tot += red[g2][tid];
        totals[tid] = tot;
    }
    __syncthreads();
    if (tid == 0) {
        double acc = 0.0;
#pragma unroll
        for (int o2 = 0; o2 < 10; ++o2) {
            double h1 = totals[o2] + (double)b1[o2];
            h1 = (h1 > 0.0) ? h1 : 0.01 * h1;
            acc += (double)W2[o2] * h1;
        }
        double shat = acc + (double)b2[0];
        out[0] = (float)shat;
        double ssum = totals[10], ssum2 = totals[11];
        double loss = (double)NROW * shat * shat - 2.0 * shat * ssum + ssum2;
        out[1 + NROW] = (float)loss;
    }
}

extern "C" void kernel_launch(void* const* d_in, const int* in_sizes, int n_in,
                              void* d_out, int out_size, void* d_ws, size_t ws_size,
                              hipStream_t stream) {
    const float* x   = (const float*)d_in[0];
    const float* soc = (const float*)d_in[1];
    const float* ti  = (const float*)d_in[2];
    const float* tj  = (const float*)d_in[3];
    const float* W1  = (const float*)d_in[4];
    const float* b1  = (const float*)d_in[5];
    const float* W2  = (const float*)d_in[6];
    const float* b2  = (const float*)d_in[7];
    float* out = (float*)d_out;

    float*  wglob    = (float*)d_ws;
    double* partials = (double*)((char*)d_ws + WOFF_P);

    setup_kernel<<<1, 64, 0, stream>>>(ti, tj, wglob);
    main_kernel<<<NB, 64, 0, stream>>>(x, soc, W1, wglob, out + 1, partials);
    finalize_kernel<<<1, 256, 0, stream>>>(partials, b1, W2, b2, out);
}

// Round 4
// 279.137 us; speedup vs baseline: 1.2961x; 1.2961x over previous
//
#include <hip/hip_runtime.h>

#define NROW 524288
#define KDIM 66
#define NSEG 65
#define NB   2048
#define TILES (NROW / 64)      // 8192
#define PART_STRIDE 12

// ws layout: [0, 528): float weights wI[66], wJ[66]
//            [528, 528 + NB*12*8): double partials (10 h1 accs, sum_soc, sum_soc2)
#define WOFF_P 528

// ---------------------------------------------------------------------------
// Compile-time precomputation of everything input-independent:
// the f32 knot grid (replicating np.linspace(0,1,66).astype(f32)), f32 dx,
// and the f64 Thomas factorization of A^T (av, 1/w, cp), plus boundary
// coefficients. After full unroll these are all inline literals — the round-3
// profile showed the runtime version spilled ~5.3 KB/thread to scratch
// (FETCH 84.75 KB / WRITE 36 KB, 93.7 us for a 2-thread kernel).
// ---------------------------------------------------------------------------
struct Pre {
    float  xk[KDIM];
    float  dxf[NSEG];
    double av[KDIM];      // A^T lower diag
    double winv[KDIM];    // 1 / pivot
    double cp[KDIM];      // Thomas upper coeff
    double dxinv[NSEG];   // 1 / dx  (f64)
    double d3[NSEG];      // 3 * dx  (f64)
    double pp, qq, r1, r2;
};

constexpr Pre make_pre() {
    Pre p{};
    for (int k = 0; k < KDIM; ++k) p.xk[k] = (float)((1.0 / 65.0) * (double)k);
    p.xk[KDIM - 1] = 1.0f;
    for (int k = 0; k < NSEG; ++k) p.dxf[k] = p.xk[k + 1] - p.xk[k];

    double d02 = (double)(p.xk[2] - p.xk[0]);
    double dl  = (double)(p.xk[KDIM - 1] - p.xk[KDIM - 3]);

    double bv[KDIM] = {};
    double cv[KDIM] = {};
    bv[0] = (double)p.dxf[1];
    bv[KDIM - 1] = (double)p.dxf[KDIM - 3];
    for (int i = 1; i < KDIM - 1; ++i)
        bv[i] = 2.0 * ((double)p.dxf[i] + (double)p.dxf[i - 1]);
    p.av[0] = 0.0;
    p.av[1] = d02;
    for (int i = 2; i < KDIM; ++i) p.av[i] = (double)p.dxf[i - 2];
    for (int i = 0; i < KDIM - 2; ++i) cv[i] = (double)p.dxf[i + 1];
    cv[KDIM - 2] = dl;
    cv[KDIM - 1] = 0.0;

    double w = bv[0];
    p.winv[0] = 1.0 / w;
    p.cp[0]   = cv[0] / w;
    for (int i = 1; i < KDIM; ++i) {
        w = bv[i] - p.av[i] * p.cp[i - 1];
        p.winv[i] = 1.0 / w;
        p.cp[i]   = cv[i] / w;
    }
    for (int m = 0; m < NSEG; ++m) {
        p.dxinv[m] = 1.0 / (double)p.dxf[m];
        p.d3[m]    = 3.0 * (double)p.dxf[m];
    }
    p.pp = ((double)p.dxf[0] + 2.0 * d02) * (double)p.dxf[1] / d02;
    p.qq = (double)p.dxf[0] * (double)p.dxf[0] / d02;
    p.r1 = (double)p.dxf[64] * (double)p.dxf[64] / dl;
    p.r2 = (2.0 * dl + (double)p.dxf[64]) * (double)p.dxf[63] / dl;
    return p;
}

__device__ constexpr Pre PRE = make_pre();

// ---------------------------------------------------------------------------
// Setup: only the runtime-dependent sweeps remain. dp/z live in LDS (not
// scratch); wsl/wy are fused register chains emitting wo[] directly.
// Thread 0 handles t=i, thread 1 handles t=j.
// ---------------------------------------------------------------------------
__global__ __launch_bounds__(64) void setup_kernel(const float* __restrict__ ti,
                                                   const float* __restrict__ tj,
                                                   float* __restrict__ wout) {
    __shared__ double dp_s[2][KDIM];
    __shared__ double z_s[2][KDIM];
    const int tid = threadIdx.x;
    if (tid >= 2) return;
    const float t = (tid == 0) ? ti[0] : tj[0];
    float* wo = wout + tid * KDIM;

    // searchsorted(xk, t, 'right')-1 clipped to [0,64]; track xk[kk], xk[kk+1]
    // as predicated literal moves (no runtime-indexed array access).
    int kk = 0;
    float xkk = PRE.xk[0], xkk1 = PRE.xk[1];
#pragma unroll
    for (int k = 0; k <= KDIM - 2; ++k) {
        if (PRE.xk[k] <= t) { kk = k; xkk = PRE.xk[k]; xkk1 = PRE.xk[k + 1]; }
    }

    const double h  = (double)(xkk1 - xkk);
    const double u  = (double)(t - xkk);
    const double u2 = u * u, u3 = u2 * u, h2 = h * h;
    const double alpha = u3 / h2 - 2.0 * u2 / h + u;
    const double beta  = u3 / h2 - u2 / h;
    const double gamma = 3.0 * u2 / h - 2.0 * u3 / h2;

    // forward sweep: dp[i] = (rhs[i] - av[i]*dp[i-1]) / w[i]
    double dpv = 0.0;
#pragma unroll
    for (int i = 0; i < KDIM; ++i) {
        double rhs = (i == kk) ? alpha : ((i == kk + 1) ? beta : 0.0);
        dpv = (rhs - PRE.av[i] * dpv) * PRE.winv[i];
        dp_s[tid][i] = dpv;
    }

    // back substitution: z[i] = dp[i] - cp[i]*z[i+1]
    double zv = dp_s[tid][KDIM - 1];
    z_s[tid][KDIM - 1] = zv;
#pragma unroll
    for (int i = KDIM - 2; i >= 0; --i) {
        zv = dp_s[tid][i] - PRE.cp[i] * zv;
        z_s[tid][i] = zv;
    }

    // fused wsl->wy chain:
    // wsl[m] = 3(z_m dx_{m-1} + z_{m+1} dx_{m+1}) interior, boundary pp/qq/r1/r2,
    //          + gamma at kk
    // wy[m]  = wsl[m-1]/dx[m-1] - wsl[m]/dx[m]  (+1 at kk)
    const double z0  = z_s[tid][0];
    const double z65 = z_s[tid][KDIM - 1];
    double c = z0 * PRE.pp;       // partial of wsl[j-1] entering step j
    double carryW = 0.0;          // wsl[j-2]/dx[j-2]
#pragma unroll
    for (int j = 1; j <= 64; ++j) {
        const double zj = z_s[tid][j];
        double full = c + zj * PRE.d3[j];
        if (j - 1 == kk) full += gamma;
        if (j == 64)     full += z65 * PRE.r1;   // extra into wsl[63]
        const double w = full * PRE.dxinv[j - 1];
        double wy = carryW - w;
        if (j - 1 == kk) wy += 1.0;
        wo[j - 1] = (float)wy;
        carryW = w;
        c = zj * PRE.d3[j - 1];
        if (j == 1) c += z0 * PRE.qq;            // extra into wsl[1]
    }
    double full64 = c + z65 * PRE.r2;
    if (kk == 64) full64 += gamma;
    const double w64 = full64 * PRE.dxinv[64];
    double wy64 = carryW - w64;
    if (kk == 64) wy64 += 1.0;
    wo[64] = (float)wy64;
    wo[65] = (float)w64;
}

// ---------------------------------------------------------------------------
// Main streaming pass (unchanged from round 3): one wave per block; block
// stages 64 rows (16.9 KB) into LDS with coalesced float4 loads, lane l dots
// row l against wI/wJ, writes ndis, accumulates W1-partials + soc sums (f64).
// W1/soc prefetched before the staging burst. No atomics.
// ---------------------------------------------------------------------------
__global__ __launch_bounds__(64) void main_kernel(
    const float* __restrict__ x, const float* __restrict__ soc,
    const float* __restrict__ W1, const float* __restrict__ wglob,
    float* __restrict__ out_ndis, double* __restrict__ partials)
{
    __shared__ float tile[64 * KDIM];       // 16896 B
    __shared__ float wlds[2 * KDIM];        // 528 B
    const int lane = threadIdx.x;

    wlds[lane]      = wglob[lane];
    wlds[64 + lane] = wglob[64 + lane];
    if (lane < 2 * KDIM - 128) wlds[128 + lane] = wglob[128 + lane];

    double accw[10];
#pragma unroll
    for (int o = 0; o < 10; ++o) accw[o] = 0.0;
    double accs = 0.0, accs2 = 0.0;

    for (int t = blockIdx.x; t < TILES; t += NB) {
        const int n = t * 64 + lane;

        float w1v[10];
#pragma unroll
        for (int o = 0; o < 10; ++o) w1v[o] = W1[(size_t)o * NROW + n];
        float socv = soc[n];

        __syncthreads();    // protect LDS reuse (and weight visibility, iter 0)
        const float4* __restrict__ src4 =
            (const float4*)(x + (size_t)t * (64 * KDIM));
        float4* dst4 = (float4*)tile;
#pragma unroll
        for (int it = 0; it < 16; ++it)
            dst4[it * 64 + lane] = src4[it * 64 + lane];
        const float2* __restrict__ src2 =
            (const float2*)(x + (size_t)t * (64 * KDIM)) + 2048;
        ((float2*)tile)[2048 + lane] = src2[lane];
        __syncthreads();

        const float2* row = (const float2*)tile + lane * (KDIM / 2);  // 264 B stride: 2-way bank alias (free)
        const float2* wi2 = (const float2*)wlds;
        const float2* wj2 = wi2 + (KDIM / 2);
        float ri = 0.f, rj = 0.f;
#pragma unroll
        for (int k = 0; k < KDIM / 2; ++k) {
            float2 v = row[k];
            float2 a = wi2[k];
            float2 b = wj2[k];
            ri = fmaf(v.x, a.x, ri); ri = fmaf(v.y, a.y, ri);
            rj = fmaf(v.x, b.x, rj); rj = fmaf(v.y, b.y, rj);
        }

        float nd = (ri - rj) / (ri + rj);
        out_ndis[n] = nd;

        double ndd = (double)nd;
#pragma unroll
        for (int o = 0; o < 10; ++o)
            accw[o] = fma((double)w1v[o], ndd, accw[o]);
        double sv = (double)socv;
        accs  += sv;
        accs2  = fma(sv, sv, accs2);
    }

    // wave-level reduction of the 12 f64 accumulators
#pragma unroll
    for (int o = 0; o < 10; ++o) {
        double v = accw[o];
#pragma unroll
        for (int off = 32; off > 0; off >>= 1) v += __shfl_down(v, off, 64);
        accw[o] = v;
    }
    {
        double v = accs;
#pragma unroll
        for (int off = 32; off > 0; off >>= 1) v += __shfl_down(v, off, 64);
        accs = v;
        v = accs2;
#pragma unroll
        for (int off = 32; off > 0; off >>= 1) v += __shfl_down(v, off, 64);
        accs2 = v;
    }
    if (lane == 0) {
        double* p = partials + (size_t)blockIdx.x * PART_STRIDE;
#pragma unroll
        for (int o = 0; o < 10; ++o) p[o] = accw[o];
        p[10] = accs;
        p[11] = accs2;
    }
}

// ---------------------------------------------------------------------------
// Finalize: reduce 2048x12 partials, apply b1 / leaky-relu / W2 / b2, and the
// closed-form loss  N*s^2 - 2*s*sum(soc) + sum(soc^2).
// ---------------------------------------------------------------------------
__global__ void finalize_kernel(const double* __restrict__ partials,
                                const float* __restrict__ b1,
                                const float* __restrict__ W2,
                                const float* __restrict__ b2,
                                float* __restrict__ out)
{
    __shared__ double red[16][16];
    __shared__ double totals[12];
    int tid = threadIdx.x;
    int o = tid & 15, g = tid >> 4;     // 16 groups x 16 slots (12 used)
    double s = 0.0;
    if (o < 12) {
        for (int b = g; b < NB; b += 16)
            s += partials[(size_t)b * PART_STRIDE + o];
    }
    red[g][o] = s;
    __syncthreads();
    if (tid < 12) {
        double tot = 0.0;
        for (int g2 = 0; g2 < 16; ++g2) tot += red[g2][tid];
        totals[tid] = tot;
    }
    __syncthreads();
    if (tid == 0) {
        double acc = 0.0;
#pragma unroll
        for (int o2 = 0; o2 < 10; ++o2) {
            double h1 = totals[o2] + (double)b1[o2];
            h1 = (h1 > 0.0) ? h1 : 0.01 * h1;
            acc += (double)W2[o2] * h1;
        }
        double shat = acc + (double)b2[0];
        out[0] = (float)shat;
        double ssum = totals[10], ssum2 = totals[11];
        double loss = (double)NROW * shat * shat - 2.0 * shat * ssum + ssum2;
        out[1 + NROW] = (float)loss;
    }
}

extern "C" void kernel_launch(void* const* d_in, const int* in_sizes, int n_in,
                              void* d_out, int out_size, void* d_ws, size_t ws_size,
                              hipStream_t stream) {
    const float* x   = (const float*)d_in[0];
    const float* soc = (const float*)d_in[1];
    const float* ti  = (const float*)d_in[2];
    const float* tj  = (const float*)d_in[3];
    const float* W1  = (const float*)d_in[4];
    const float* b1  = (const float*)d_in[5];
    const float* W2  = (const float*)d_in[6];
    const float* b2  = (const float*)d_in[7];
    float* out = (float*)d_out;

    float*  wglob    = (float*)d_ws;
    double* partials = (double*)((char*)d_ws + WOFF_P);

    setup_kernel<<<1, 64, 0, stream>>>(ti, tj, wglob);
    main_kernel<<<NB, 64, 0, stream>>>(x, soc, W1, wglob, out + 1, partials);
    finalize_kernel<<<1, 256, 0, stream>>>(partials, b1, W2, b2, out);
}

// Round 5
// 278.729 us; speedup vs baseline: 1.2980x; 1.0015x over previous
//
#include <hip/hip_runtime.h>

#define NROW 524288
#define KDIM 66
#define NSEG 65
#define NB   2048
#define PART_STRIDE 12

// ws layout: [0, 528): float weights wI[66], wJ[66]
//            [528, 528 + NB*12*8): double partials (10 h1 accs, sum_soc, sum_soc2)
#define WOFF_P 528

// ---------------------------------------------------------------------------
// Compile-time precomputation of everything input-independent (round-4 fix:
// the runtime version spilled ~5.3 KB/thread to scratch, 93.7 us).
// ---------------------------------------------------------------------------
struct Pre {
    float  xk[KDIM];
    float  dxf[NSEG];
    double av[KDIM];      // A^T lower diag
    double winv[KDIM];    // 1 / pivot
    double cp[KDIM];      // Thomas upper coeff
    double dxinv[NSEG];   // 1 / dx  (f64)
    double d3[NSEG];      // 3 * dx  (f64)
    double pp, qq, r1, r2;
};

constexpr Pre make_pre() {
    Pre p{};
    for (int k = 0; k < KDIM; ++k) p.xk[k] = (float)((1.0 / 65.0) * (double)k);
    p.xk[KDIM - 1] = 1.0f;
    for (int k = 0; k < NSEG; ++k) p.dxf[k] = p.xk[k + 1] - p.xk[k];

    double d02 = (double)(p.xk[2] - p.xk[0]);
    double dl  = (double)(p.xk[KDIM - 1] - p.xk[KDIM - 3]);

    double bv[KDIM] = {};
    double cv[KDIM] = {};
    bv[0] = (double)p.dxf[1];
    bv[KDIM - 1] = (double)p.dxf[KDIM - 3];
    for (int i = 1; i < KDIM - 1; ++i)
        bv[i] = 2.0 * ((double)p.dxf[i] + (double)p.dxf[i - 1]);
    p.av[0] = 0.0;
    p.av[1] = d02;
    for (int i = 2; i < KDIM; ++i) p.av[i] = (double)p.dxf[i - 2];
    for (int i = 0; i < KDIM - 2; ++i) cv[i] = (double)p.dxf[i + 1];
    cv[KDIM - 2] = dl;
    cv[KDIM - 1] = 0.0;

    double w = bv[0];
    p.winv[0] = 1.0 / w;
    p.cp[0]   = cv[0] / w;
    for (int i = 1; i < KDIM; ++i) {
        w = bv[i] - p.av[i] * p.cp[i - 1];
        p.winv[i] = 1.0 / w;
        p.cp[i]   = cv[i] / w;
    }
    for (int m = 0; m < NSEG; ++m) {
        p.dxinv[m] = 1.0 / (double)p.dxf[m];
        p.d3[m]    = 3.0 * (double)p.dxf[m];
    }
    p.pp = ((double)p.dxf[0] + 2.0 * d02) * (double)p.dxf[1] / d02;
    p.qq = (double)p.dxf[0] * (double)p.dxf[0] / d02;
    p.r1 = (double)p.dxf[64] * (double)p.dxf[64] / dl;
    p.r2 = (2.0 * dl + (double)p.dxf[64]) * (double)p.dxf[63] / dl;
    return p;
}

__device__ constexpr Pre PRE = make_pre();

// ---------------------------------------------------------------------------
// Setup (unchanged from round 4 — verified): runtime-dependent sweeps only;
// dp/z in LDS; fused wsl->wy register chain. Thread 0: t=i, thread 1: t=j.
// ---------------------------------------------------------------------------
__global__ __launch_bounds__(64) void setup_kernel(const float* __restrict__ ti,
                                                   const float* __restrict__ tj,
                                                   float* __restrict__ wout) {
    __shared__ double dp_s[2][KDIM];
    __shared__ double z_s[2][KDIM];
    const int tid = threadIdx.x;
    if (tid >= 2) return;
    const float t = (tid == 0) ? ti[0] : tj[0];
    float* wo = wout + tid * KDIM;

    int kk = 0;
    float xkk = PRE.xk[0], xkk1 = PRE.xk[1];
#pragma unroll
    for (int k = 0; k <= KDIM - 2; ++k) {
        if (PRE.xk[k] <= t) { kk = k; xkk = PRE.xk[k]; xkk1 = PRE.xk[k + 1]; }
    }

    const double h  = (double)(xkk1 - xkk);
    const double u  = (double)(t - xkk);
    const double u2 = u * u, u3 = u2 * u, h2 = h * h;
    const double alpha = u3 / h2 - 2.0 * u2 / h + u;
    const double beta  = u3 / h2 - u2 / h;
    const double gamma = 3.0 * u2 / h - 2.0 * u3 / h2;

    double dpv = 0.0;
#pragma unroll
    for (int i = 0; i < KDIM; ++i) {
        double rhs = (i == kk) ? alpha : ((i == kk + 1) ? beta : 0.0);
        dpv = (rhs - PRE.av[i] * dpv) * PRE.winv[i];
        dp_s[tid][i] = dpv;
    }

    double zv = dp_s[tid][KDIM - 1];
    z_s[tid][KDIM - 1] = zv;
#pragma unroll
    for (int i = KDIM - 2; i >= 0; --i) {
        zv = dp_s[tid][i] - PRE.cp[i] * zv;
        z_s[tid][i] = zv;
    }

    const double z0  = z_s[tid][0];
    const double z65 = z_s[tid][KDIM - 1];
    double c = z0 * PRE.pp;
    double carryW = 0.0;
#pragma unroll
    for (int j = 1; j <= 64; ++j) {
        const double zj = z_s[tid][j];
        double full = c + zj * PRE.d3[j];
        if (j - 1 == kk) full += gamma;
        if (j == 64)     full += z65 * PRE.r1;
        const double w = full * PRE.dxinv[j - 1];
        double wy = carryW - w;
        if (j - 1 == kk) wy += 1.0;
        wo[j - 1] = (float)wy;
        carryW = w;
        c = zj * PRE.d3[j - 1];
        if (j == 1) c += z0 * PRE.qq;
    }
    double full64 = c + z65 * PRE.r2;
    if (kk == 64) full64 += gamma;
    const double w64 = full64 * PRE.dxinv[64];
    double wy64 = carryW - w64;
    if (kk == 64) wy64 += 1.0;
    wo[64] = (float)wy64;
    wo[65] = (float)w64;
}

// ---------------------------------------------------------------------------
// Main pass, restructured: ONE ROW PER THREAD, no LDS staging of x, no
// per-tile barriers. Lane reads its own 264 B row as 33x float2 (rows are
// only 8B-aligned), dots against weights broadcast from LDS (uniform addr),
// writes ndis, accumulates W1/soc terms in f64. Block reduction: wave
// shuffle + one LDS hop (the only barriers, at kernel end).
// ---------------------------------------------------------------------------
__global__ __launch_bounds__(256) void main_kernel(
    const float* __restrict__ x, const float* __restrict__ soc,
    const float* __restrict__ W1, const float* __restrict__ wglob,
    float* __restrict__ out_ndis, double* __restrict__ partials)
{
    __shared__ __align__(16) float wi_s[KDIM];
    __shared__ __align__(16) float wj_s[KDIM];
    __shared__ double red[4][12];
    const int tid = threadIdx.x;

    if (tid < KDIM)            wi_s[tid]        = wglob[tid];
    else if (tid < 2 * KDIM)   wj_s[tid - KDIM] = wglob[tid];
    __syncthreads();

    const int n = blockIdx.x * 256 + tid;

    // Independent per-row operands issued first (oldest in flight).
    float w1v[10];
#pragma unroll
    for (int o = 0; o < 10; ++o) w1v[o] = W1[(size_t)o * NROW + n];
    const float socv = soc[n];

    const float2* __restrict__ row = (const float2*)(x + (size_t)n * KDIM);
    const float2* wi2 = (const float2*)wi_s;
    const float2* wj2 = (const float2*)wj_s;
    float ri = 0.f, rj = 0.f;
#pragma unroll
    for (int k = 0; k < KDIM / 2; ++k) {
        const float2 v = row[k];
        const float2 a = wi2[k];
        const float2 b = wj2[k];
        ri = fmaf(v.x, a.x, ri); ri = fmaf(v.y, a.y, ri);
        rj = fmaf(v.x, b.x, rj); rj = fmaf(v.y, b.y, rj);
    }

    const float nd = (ri - rj) / (ri + rj);
    out_ndis[n] = nd;

    // 12 f64 accumulators for this thread's single row.
    const double ndd = (double)nd;
    double acc[12];
#pragma unroll
    for (int o = 0; o < 10; ++o) acc[o] = (double)w1v[o] * ndd;
    const double sv = (double)socv;
    acc[10] = sv;
    acc[11] = sv * sv;

    // wave-level shuffle reduction
#pragma unroll
    for (int o = 0; o < 12; ++o) {
        double v = acc[o];
#pragma unroll
        for (int off = 32; off > 0; off >>= 1) v += __shfl_down(v, off, 64);
        acc[o] = v;
    }
    const int wid  = tid >> 6;
    const int lane = tid & 63;
    if (lane == 0) {
#pragma unroll
        for (int o = 0; o < 12; ++o) red[wid][o] = acc[o];
    }
    __syncthreads();
    if (tid < 12) {
        double s = red[0][tid] + red[1][tid] + red[2][tid] + red[3][tid];
        partials[(size_t)blockIdx.x * PART_STRIDE + tid] = s;
    }
}

// ---------------------------------------------------------------------------
// Finalize (unchanged): reduce 2048x12 partials, b1 / leaky-relu / W2 / b2,
// closed-form loss  N*s^2 - 2*s*sum(soc) + sum(soc^2).
// ---------------------------------------------------------------------------
__global__ void finalize_kernel(const double* __restrict__ partials,
                                const float* __restrict__ b1,
                                const float* __restrict__ W2,
                                const float* __restrict__ b2,
                                float* __restrict__ out)
{
    __shared__ double red[16][16];
    __shared__ double totals[12];
    int tid = threadIdx.x;
    int o = tid & 15, g = tid >> 4;     // 16 groups x 16 slots (12 used)
    double s = 0.0;
    if (o < 12) {
        for (int b = g; b < NB; b += 16)
            s += partials[(size_t)b * PART_STRIDE + o];
    }
    red[g][o] = s;
    __syncthreads();
    if (tid < 12) {
        double tot = 0.0;
        for (int g2 = 0; g2 < 16; ++g2) tot += red[g2][tid];
        totals[tid] = tot;
    }
    __syncthreads();
    if (tid == 0) {
        double acc = 0.0;
#pragma unroll
        for (int o2 = 0; o2 < 10; ++o2) {
            double h1 = totals[o2] + (double)b1[o2];
            h1 = (h1 > 0.0) ? h1 : 0.01 * h1;
            acc += (double)W2[o2] * h1;
        }
        double shat = acc + (double)b2[0];
        out[0] = (float)shat;
        double ssum = totals[10], ssum2 = totals[11];
        double loss = (double)NROW * shat * shat - 2.0 * shat * ssum + ssum2;
        out[1 + NROW] = (float)loss;
    }
}

extern "C" void kernel_launch(void* const* d_in, const int* in_sizes, int n_in,
                              void* d_out, int out_size, void* d_ws, size_t ws_size,
                              hipStream_t stream) {
    const float* x   = (const float*)d_in[0];
    const float* soc = (const float*)d_in[1];
    const float* ti  = (const float*)d_in[2];
    const float* tj  = (const float*)d_in[3];
    const float* W1  = (const float*)d_in[4];
    const float* b1  = (const float*)d_in[5];
    const float* W2  = (const float*)d_in[6];
    const float* b2  = (const float*)d_in[7];
    float* out = (float*)d_out;

    float*  wglob    = (float*)d_ws;
    double* partials = (double*)((char*)d_ws + WOFF_P);

    setup_kernel<<<1, 64, 0, stream>>>(ti, tj, wglob);
    main_kernel<<<NB, 256, 0, stream>>>(x, soc, W1, wglob, out + 1, partials);
    finalize_kernel<<<1, 256, 0, stream>>>(partials, b1, W2, b2, out);
}